// Round 19
// baseline (207.146 us; speedup 1.0000x reference)
//
#include <hip/hip_runtime.h>
#include <hip/hip_bf16.h>

typedef __attribute__((ext_vector_type(8))) short short8;
typedef __attribute__((ext_vector_type(4))) float float4v;
typedef unsigned int uint;

#define NBLK 192  // blocks for hist/scatterbin passes

static __device__ __forceinline__ float2 up_bf2(uint v) {
    float2 r;
    r.x = __uint_as_float(v << 16);
    r.y = __uint_as_float(v & 0xffff0000u);
    return r;
}
static __device__ __forceinline__ short f2bf_bits(float x) {
    union { __hip_bfloat16 h; short s; } u;
    u.h = __float2bfloat16(x);
    return u.s;
}

// ---------------- per-(bucket,block) histogram + W1-fragment prebuild ----------------
// Blocks < NBLK: LDS histogram of dst buckets. Blocks >= NBLK (8 of them):
// build W1frag[ctile][lane][8] bf16 (B-frag for 16x16x32: lane holds
// B[k=quad*8+j][col=ctile*16+(lane&15)], k>=9 -> 0).

__global__ __launch_bounds__(256) void k_hist(const int* __restrict__ dst, int E, int chunk,
        int shift, int nbuck, int* __restrict__ histBlk,
        const float* __restrict__ W1, __hip_bfloat16* __restrict__ W1frag) {
    int blk = blockIdx.x;
    if (blk >= NBLK) {
        int t = (blk - NBLK) * 256 + threadIdx.x;  // 2048 total = 32 ctiles x 64 lanes
        int ctile = t >> 6, lane = t & 63;
        int col = ctile * 16 + (lane & 15);
        int k0 = (lane >> 4) * 8;
        short8 o;
#pragma unroll
        for (int j = 0; j < 8; ++j) {
            int k = k0 + j;
            o[j] = f2bf_bits(k < 9 ? W1[k * 512 + col] : 0.f);
        }
        *reinterpret_cast<short8*>(W1frag + (size_t)t * 8) = o;
        return;
    }
    __shared__ int h[256];
    h[threadIdx.x] = 0;
    __syncthreads();
    int e0 = blk * chunk, e1 = min(E, e0 + chunk);
    for (int e = e0 + threadIdx.x; e < e1; e += 256)
        atomicAdd(&h[dst[e] >> shift], 1);
    __syncthreads();
    if (threadIdx.x < nbuck) histBlk[threadIdx.x * NBLK + blk] = h[threadIdx.x];
}

// ---------------- per-(bucket,block) bases + bucket bases ----------------
// Cross-bucket base computed in-kernel (sum of all histBlk entries of lower
// buckets, L2-hot) -- replaces the former k_btot dispatch.

__global__ __launch_bounds__(256) void k_bscan(const int* __restrict__ histBlk,
        int nbuck, int* __restrict__ baseBlk, int* __restrict__ bucketBase) {
    __shared__ int s[256], red[256];
    int b = blockIdx.x, t = threadIdx.x;
    // base = total edges in buckets < b
    int partial = 0;
    for (int idx = t; idx < b * NBLK; idx += 256) partial += histBlk[idx];
    red[t] = partial;
    __syncthreads();
    for (int off = 128; off; off >>= 1) {
        if (t < off) red[t] += red[t + off];
        __syncthreads();
    }
    int base = red[0];
    // scan own bucket's NBLK per-block counts
    int v = (t < NBLK) ? histBlk[b * NBLK + t] : 0;
    s[t] = v;
    __syncthreads();
    for (int off = 1; off < 256; off <<= 1) {
        int u = (t >= off) ? s[t - off] : 0;
        __syncthreads();
        s[t] += u;
        __syncthreads();
    }
    if (t < NBLK) baseBlk[b * NBLK + t] = base + s[t] - v;
    if (t == 0) bucketBase[b] = base;
}

// ---------------- scatter into per-(bucket,block) slices, packed payload ----------------
// binned word = src (24b) | dst_local (8b).  Requires n < 2^24 and shift == 8.

__global__ __launch_bounds__(256) void k_scatterbin(const int* __restrict__ src,
        const int* __restrict__ dst, int E, int chunk, int shift, int nbuck,
        const int* __restrict__ baseBlk, uint* __restrict__ binned) {
    __shared__ int cur[256];
    int blk = blockIdx.x;
    if (threadIdx.x < nbuck) cur[threadIdx.x] = baseBlk[threadIdx.x * NBLK + blk];
    __syncthreads();
    int e0 = blk * chunk, e1 = min(E, e0 + chunk);
    int mask = (1 << shift) - 1;
    for (int e = e0 + threadIdx.x; e < e1; e += 256) {
        int d = dst[e];
        int pos = atomicAdd(&cur[d >> shift], 1);
        binned[pos] = (uint)src[e] | ((uint)(d & mask) << 24);
    }
}

// ---------------- per-bucket: counts -> row_ptr/dinv/xs, then exact csr scatter ----------------

__global__ __launch_bounds__(256) void k_csrbuild(const uint* __restrict__ binned,
        const int* __restrict__ bucketBase, const float* __restrict__ x,
        int E, int shift, int n, int nbuck,
        int* __restrict__ row_ptr, float* __restrict__ dinv, float* __restrict__ xs,
        int* __restrict__ csr) {
    __shared__ int cnt[256], lcur[256];
    int b = blockIdx.x, t = threadIdx.x;
    cnt[t] = 0;
    __syncthreads();
    int lo = bucketBase[b];
    int hi = (b + 1 < nbuck) ? bucketBase[b + 1] : E;
    for (int e = lo + t; e < hi; e += 256)
        atomicAdd(&cnt[binned[e] >> 24], 1);
    __syncthreads();
    int c = cnt[t];
    lcur[t] = c;
    __syncthreads();
    for (int off = 1; off < 256; off <<= 1) {
        int u = (t >= off) ? lcur[t - off] : 0;
        __syncthreads();
        lcur[t] += u;
        __syncthreads();
    }
    int node0 = b << shift;
    int nodeEnd = min(n, (b + 1) << shift);
    int cntNodes = nodeEnd - node0;
    int myBase = lo + lcur[t] - c;  // exclusive prefix within bucket
    if (t < cntNodes) {
        row_ptr[node0 + t] = myBase;
        dinv[node0 + t] = rsqrtf((float)(c + 1));  // +1 self-loop
    }
    if (b == nbuck - 1 && t == 0) row_ptr[n] = E;
    for (int j = t; j < cntNodes * 9; j += 256) {
        int nl = j / 9, f = j - nl * 9;
        float dnl = rsqrtf((float)(cnt[nl] + 1));
        xs[(size_t)(node0 + nl) * 9 + f] = dnl * x[(size_t)(node0 + nl) * 9 + f];
    }
    __syncthreads();
    lcur[t] = myBase;  // running cursors
    __syncthreads();
    for (int e = lo + t; e < hi; e += 256) {
        uint p = binned[e];
        int pos = atomicAdd(&lcur[p >> 24], 1);
        csr[pos] = (int)(p & 0xFFFFFF);
    }
}

// ---------------- Layer 1 aggregate: aggx_bf = bf16(dinv .* (sum xs)) [node][32] ----------------
// Output padded to K=32 (cols 9..31 zero) in bf16: directly MFMA-A-consumable.

__global__ __launch_bounds__(256) void k_agg1(const float* __restrict__ xs,
                       const float* __restrict__ dinv,
                       const int* __restrict__ row_ptr, const int* __restrict__ csr,
                       __hip_bfloat16* __restrict__ aggx_bf, int n) {
    int node = blockIdx.x * 16 + (threadIdx.x >> 4);
    if (node >= n) return;
    int f = threadIdx.x & 15;
    bool act = f < 9;
    float acc = act ? xs[node * 9 + f] : 0.f;  // self-loop (xs = dinv*x)
    int e0 = row_ptr[node], e1 = row_ptr[node + 1];
    int e = e0;
    for (; e + 4 <= e1; e += 4) {
        int s0 = csr[e], s1 = csr[e + 1], s2 = csr[e + 2], s3 = csr[e + 3];
        float x0 = act ? xs[s0 * 9 + f] : 0.f;
        float x1 = act ? xs[s1 * 9 + f] : 0.f;
        float x2 = act ? xs[s2 * 9 + f] : 0.f;
        float x3 = act ? xs[s3 * 9 + f] : 0.f;
        acc += (x0 + x1) + (x2 + x3);
    }
    for (; e < e1; ++e) {
        int sA = csr[e];
        acc += act ? xs[sA * 9 + f] : 0.f;
    }
    float v = act ? dinv[node] * acc : 0.f;
    __hip_bfloat16* op = aggx_bf + (size_t)node * 32;
    union { __hip_bfloat16 h; short s; } u;
    u.h = __float2bfloat16(v);
    reinterpret_cast<short*>(op)[f] = u.s;
    reinterpret_cast<short*>(op)[16 + f] = 0;
}

// ---------------- Fused layer1-MFMA + layer2 GEMM ----------------
// r18 structure (h1 via MFMA, same-wave LDS relayout, W1frag table); pairs now
// spread over 256 blocks (was 196) -- per-CU work -23%, still one block-round.
__global__ __launch_bounds__(512, 2) void k_l12(const __hip_bfloat16* __restrict__ aggx_bf,
                       const __hip_bfloat16* __restrict__ W1frag, const float* __restrict__ b1,
                       const float* __restrict__ W2, const float* __restrict__ dinv,
                       __hip_bfloat16* __restrict__ t2, int n, int npair) {
    __shared__ short bsh[64 * 128 * 8];  // 128 KB: [kb 0..63][c 0..127][j 0..7]
    __shared__ short h1s[8][16][40];     // 10 KB: per-wave 16 rows x 32 cols, stride 40
    int t = threadIdx.x;

    // Stage all 128 cols of W2 (fp32 -> bf16) into LDS.
    for (int idx = t; idx < 64 * 128; idx += 512) {
        int kb = idx >> 7, c = idx & 127;
        const float* wp = W2 + (size_t)(kb * 8) * 128 + c;
        short8 o;
#pragma unroll
        for (int j = 0; j < 8; ++j) o[j] = f2bf_bits(wp[j * 128]);
        *reinterpret_cast<short8*>(bsh + (size_t)idx * 8) = o;
    }
    __syncthreads();

    int wid = t >> 6, lane = t & 63;
    int pair = wid * gridDim.x + blockIdx.x;
    if (pair >= npair) return;
    int r = lane & 15, quad = lane >> 4;
    short (*hs)[40] = h1s[wid];

#pragma unroll
    for (int half = 0; half < 2; ++half) {
        int m0 = (pair << 5) + half * 16;
        // A-frag for h1-GEMM: aggx_bf[m0+r][quad*8+j] (padded rows OOB-safe)
        short8 aagg = *reinterpret_cast<const short8*>(
            aggx_bf + (size_t)(m0 + r) * 32 + quad * 8);

        float4v acc[8];
#pragma unroll
        for (int cg = 0; cg < 8; ++cg) acc[cg] = (float4v){0, 0, 0, 0};

        for (int kt = 0; kt < 16; ++kt) {
            // h1 cols [kt*32, kt*32+32): two 16-col MFMAs
            short8 bf0 = *reinterpret_cast<const short8*>(
                W1frag + ((size_t)(2 * kt) * 64 + lane) * 8);
            short8 bf1 = *reinterpret_cast<const short8*>(
                W1frag + ((size_t)(2 * kt + 1) * 64 + lane) * 8);
            float4v c0 = __builtin_amdgcn_mfma_f32_16x16x32_bf16(
                aagg, bf0, (float4v){0, 0, 0, 0}, 0, 0, 0);
            float4v c1 = __builtin_amdgcn_mfma_f32_16x16x32_bf16(
                aagg, bf1, (float4v){0, 0, 0, 0}, 0, 0, 0);
            float bb0 = b1[kt * 32 + r];
            float bb1 = b1[kt * 32 + 16 + r];
            // C-layout (col=lane&15, row=quad*4+i) -> LDS [row][col]
#pragma unroll
            for (int i = 0; i < 4; ++i) {
                int row = quad * 4 + i;
                hs[row][r]      = f2bf_bits(fmaxf(c0[i] + bb0, 0.f));
                hs[row][16 + r] = f2bf_bits(fmaxf(c1[i] + bb1, 0.f));
            }
            // same-wave read back in A-layout: A[m=r][k=quad*8+j]
            short8 am = *reinterpret_cast<const short8*>(&hs[r][quad * 8]);
#pragma unroll
            for (int cg = 0; cg < 8; ++cg) {
                short8 b = *reinterpret_cast<const short8*>(
                    bsh + (size_t)(((kt * 4 + quad) * 128) + cg * 16 + r) * 8);
                acc[cg] = __builtin_amdgcn_mfma_f32_16x16x32_bf16(am, b, acc[cg], 0, 0, 0);
            }
        }

        // Epilogue: C/D col = lane&15, row = quad*4 + reg; scale row by dinv[node]
#pragma unroll
        for (int i = 0; i < 4; ++i) {
            int node = m0 + quad * 4 + i;
            if (node < n) {
                float di = dinv[node];
                __hip_bfloat16* op = t2 + (size_t)node * 128 + r;
#pragma unroll
                for (int cg = 0; cg < 8; ++cg)
                    op[cg * 16] = __float2bfloat16(di * acc[cg][i]);
            }
        }
    }
}

// ---------------- Layer 2 aggregate + fused layer-3 matmul ----------------

__global__ __launch_bounds__(256) void k_agg2(const uint* __restrict__ t2u,
                       const float* __restrict__ dinv,
                       const int* __restrict__ row_ptr, const int* __restrict__ csr,
                       const float* __restrict__ b2, const float* __restrict__ W3,
                       float2* __restrict__ t3, int n) {
    int node = blockIdx.x * 4 + (threadIdx.x >> 6);
    if (node >= n) return;
    int lane = threadIdx.x & 63;
    float2 p = up_bf2(t2u[(size_t)node * 64 + lane]);  // self (t2' = dinv*t2)
    float a0 = p.x, a1 = p.y;
    int e0 = row_ptr[node], e1 = row_ptr[node + 1];
    int e = e0;
    for (; e + 8 <= e1; e += 8) {
        int si[8];
        uint ri[8];
#pragma unroll
        for (int j = 0; j < 8; ++j) si[j] = csr[e + j];
#pragma unroll
        for (int j = 0; j < 8; ++j) ri[j] = t2u[(size_t)si[j] * 64 + lane];
#pragma unroll
        for (int j = 0; j < 8; ++j) {
            float2 q = up_bf2(ri[j]);
            a0 += q.x;
            a1 += q.y;
        }
    }
    for (; e + 2 <= e1; e += 2) {
        int s0 = csr[e], s1 = csr[e + 1];
        uint r0 = t2u[(size_t)s0 * 64 + lane];
        uint r1 = t2u[(size_t)s1 * 64 + lane];
        float2 q0 = up_bf2(r0), q1 = up_bf2(r1);
        a0 += q0.x + q1.x;
        a1 += q0.y + q1.y;
    }
    if (e < e1) {
        float2 q0 = up_bf2(t2u[(size_t)csr[e] * 64 + lane]);
        a0 += q0.x;
        a1 += q0.y;
    }
    float di = dinv[node];
    float2 bb = *reinterpret_cast<const float2*>(b2 + 2 * lane);
    float h0 = fmaxf(di * a0 + bb.x, 0.f);
    float h1v = fmaxf(di * a1 + bb.y, 0.f);
    float4 wv = *reinterpret_cast<const float4*>(W3 + 4 * lane);
    float c0 = h0 * wv.x + h1v * wv.z;
    float c1 = h0 * wv.y + h1v * wv.w;
#pragma unroll
    for (int off = 32; off; off >>= 1) {
        c0 += __shfl_xor(c0, off);
        c1 += __shfl_xor(c1, off);
    }
    if (lane == 0) t3[node] = make_float2(di * c0, di * c1);  // prescaled
}

// ---------------- Layer 3 aggregate + log_softmax ----------------

__global__ void k_agg3(const float2* __restrict__ t3, const float* __restrict__ dinv,
                       const int* __restrict__ row_ptr, const int* __restrict__ csr,
                       const float* __restrict__ b3, float2* __restrict__ outv, int n) {
    int node = blockIdx.x * blockDim.x + threadIdx.x;
    if (node >= n) return;
    float2 s = t3[node];  // self (t3' = dinv*t3)
    float a0 = s.x, a1 = s.y;
    int e0 = row_ptr[node], e1 = row_ptr[node + 1];
    int e = e0;
    for (; e + 4 <= e1; e += 4) {
        int s0 = csr[e], s1 = csr[e + 1], s2 = csr[e + 2], s3 = csr[e + 3];
        float2 q0 = t3[s0], q1 = t3[s1], q2 = t3[s2], q3 = t3[s3];
        a0 += q0.x + q1.x + q2.x + q3.x;
        a1 += q0.y + q1.y + q2.y + q3.y;
    }
    for (; e < e1; ++e) {
        float2 q0 = t3[csr[e]];
        a0 += q0.x;
        a1 += q0.y;
    }
    float di = dinv[node];
    float z0 = di * a0 + b3[0];
    float z1 = di * a1 + b3[1];
    float m = fmaxf(z0, z1);
    float lse = m + logf(expf(z0 - m) + expf(z1 - m));
    outv[node] = make_float2(z0 - lse, z1 - lse);
}

// ---------------- launch ----------------

extern "C" void kernel_launch(void* const* d_in, const int* in_sizes, int n_in,
                              void* d_out, int out_size, void* d_ws, size_t ws_size,
                              hipStream_t stream) {
    const float* x  = (const float*)d_in[0];
    const float* W1 = (const float*)d_in[1];
    const float* b1 = (const float*)d_in[2];
    const float* W2 = (const float*)d_in[3];
    const float* b2 = (const float*)d_in[4];
    const float* W3 = (const float*)d_in[5];
    const float* b3 = (const float*)d_in[6];
    const int* edges = (const int*)d_in[7];

    int n = in_sizes[0] / 9;
    int E = in_sizes[7] / 2;
    const int* src = edges;
    const int* dst = edges + E;

    char* p = (char*)d_ws;
    auto alloc = [&](size_t bytes) {
        char* q = p;
        p += (bytes + 511) & ~(size_t)511;
        return q;
    };
    float* dinv       = (float*)alloc((size_t)n * 4);
    int*   row_ptr    = (int*)alloc((size_t)(n + 1) * 4);
    int*   csr        = (int*)alloc((size_t)E * 4);
    int*   histBlk    = (int*)alloc((size_t)256 * NBLK * 4);
    int*   baseBlk    = (int*)alloc((size_t)256 * NBLK * 4);
    int*   bucketBase = (int*)alloc(256 * 4);
    uint*  binned     = (uint*)alloc((size_t)E * 4);
    float* xs         = (float*)alloc((size_t)n * 9 * 4);
    __hip_bfloat16* aggx_bf = (__hip_bfloat16*)alloc((size_t)(n + 64) * 32 * 2);
    __hip_bfloat16* W1frag  = (__hip_bfloat16*)alloc((size_t)32 * 64 * 8 * 2);
    __hip_bfloat16* t2 = (__hip_bfloat16*)alloc((size_t)n * 128 * 2);
    float2* t3 = (float2*)alloc((size_t)n * 8);

    const int B = 256;
    int shift = 8;  // packed binned requires shift==8 (dst_local 8b) and n < 2^24
    int nbuck = ((n - 1) >> shift) + 1;
    int chunk = (E + NBLK - 1) / NBLK;

    k_hist<<<NBLK + 8, B, 0, stream>>>(dst, E, chunk, shift, nbuck, histBlk, W1, W1frag);
    k_bscan<<<nbuck, B, 0, stream>>>(histBlk, nbuck, baseBlk, bucketBase);
    k_scatterbin<<<NBLK, B, 0, stream>>>(src, dst, E, chunk, shift, nbuck, baseBlk, binned);
    k_csrbuild<<<nbuck, B, 0, stream>>>(binned, bucketBase, x, E, shift, n, nbuck,
                                        row_ptr, dinv, xs, csr);

    k_agg1<<<(n + 15) / 16, B, 0, stream>>>(xs, dinv, row_ptr, csr, aggx_bf, n);

    int ntile = (n + 15) / 16;            // 3125
    int npair = (ntile + 1) / 2;          // 1563 wave-tasks
    int nblk12 = (npair + 7) / 8;
    if (nblk12 < 256 && npair >= 256) nblk12 = 256;  // spread over all CUs
    k_l12<<<nblk12, 512, 0, stream>>>(aggx_bf, W1frag, b1, W2, dinv, t2, n, npair);
    k_agg2<<<(n + 3) / 4, 256, 0, stream>>>((const uint*)t2, dinv, row_ptr, csr, b2, W3, t3, n);

    k_agg3<<<(n + B - 1) / B, B, 0, stream>>>(t3, dinv, row_ptr, csr, b3, (float2*)d_out, n);
}

// Round 20
// 194.166 us; speedup vs baseline: 1.0668x; 1.0668x over previous
//
#include <hip/hip_runtime.h>
#include <hip/hip_bf16.h>

typedef __attribute__((ext_vector_type(8))) short short8;
typedef __attribute__((ext_vector_type(4))) float float4v;
typedef unsigned int uint;

#define NBLK 192  // blocks for hist/scatterbin passes

static __device__ __forceinline__ float2 up_bf2(uint v) {
    float2 r;
    r.x = __uint_as_float(v << 16);
    r.y = __uint_as_float(v & 0xffff0000u);
    return r;
}
static __device__ __forceinline__ short f2bf_bits(float x) {
    union { __hip_bfloat16 h; short s; } u;
    u.h = __float2bfloat16(x);
    return u.s;
}

// ---------------- per-(bucket,block) histogram, LDS only ----------------

__global__ __launch_bounds__(256) void k_hist(const int* __restrict__ dst, int E, int chunk,
        int shift, int nbuck, int* __restrict__ histBlk) {
    __shared__ int h[256];
    h[threadIdx.x] = 0;
    __syncthreads();
    int blk = blockIdx.x;
    int e0 = blk * chunk, e1 = min(E, e0 + chunk);
    for (int e = e0 + threadIdx.x; e < e1; e += 256)
        atomicAdd(&h[dst[e] >> shift], 1);
    __syncthreads();
    if (threadIdx.x < nbuck) histBlk[threadIdx.x * NBLK + blk] = h[threadIdx.x];
}

// ---------------- bucket totals ----------------

__global__ __launch_bounds__(256) void k_btot(const int* __restrict__ histBlk,
                                              int* __restrict__ btot) {
    __shared__ int s[256];
    int b = blockIdx.x, t = threadIdx.x;
    s[t] = (t < NBLK) ? histBlk[b * NBLK + t] : 0;
    __syncthreads();
    for (int off = 128; off; off >>= 1) {
        if (t < off) s[t] += s[t + off];
        __syncthreads();
    }
    if (t == 0) btot[b] = s[0];
}

// ---------------- per-(bucket,block) bases + bucket bases ----------------

__global__ __launch_bounds__(256) void k_bscan(const int* __restrict__ histBlk,
        const int* __restrict__ btot, int nbuck,
        int* __restrict__ baseBlk, int* __restrict__ bucketBase) {
    __shared__ int s[256], sb[256];
    int b = blockIdx.x, t = threadIdx.x;
    int v = (t < NBLK) ? histBlk[b * NBLK + t] : 0;
    s[t] = v;
    sb[t] = (t < nbuck) ? btot[t] : 0;
    __syncthreads();
    for (int off = 1; off < 256; off <<= 1) {
        int u = (t >= off) ? s[t - off] : 0;
        int u2 = (t >= off) ? sb[t - off] : 0;
        __syncthreads();
        s[t] += u;
        sb[t] += u2;
        __syncthreads();
    }
    int base = (b > 0) ? sb[b - 1] : 0;  // exclusive prefix of bucket totals
    if (t < NBLK) baseBlk[b * NBLK + t] = base + s[t] - v;
    if (t == 0) bucketBase[b] = base;
}

// ---------------- scatter into per-(bucket,block) slices, packed payload ----------------
// binned word = src (24b) | dst_local (8b).  Requires n < 2^24 and shift == 8.

__global__ __launch_bounds__(256) void k_scatterbin(const int* __restrict__ src,
        const int* __restrict__ dst, int E, int chunk, int shift, int nbuck,
        const int* __restrict__ baseBlk, uint* __restrict__ binned) {
    __shared__ int cur[256];
    int blk = blockIdx.x;
    if (threadIdx.x < nbuck) cur[threadIdx.x] = baseBlk[threadIdx.x * NBLK + blk];
    __syncthreads();
    int e0 = blk * chunk, e1 = min(E, e0 + chunk);
    int mask = (1 << shift) - 1;
    for (int e = e0 + threadIdx.x; e < e1; e += 256) {
        int d = dst[e];
        int pos = atomicAdd(&cur[d >> shift], 1);
        binned[pos] = (uint)src[e] | ((uint)(d & mask) << 24);
    }
}

// ---------------- per-bucket: counts -> row_ptr/dinv/xs, then exact csr scatter ----------------

__global__ __launch_bounds__(256) void k_csrbuild(const uint* __restrict__ binned,
        const int* __restrict__ bucketBase, const float* __restrict__ x,
        int E, int shift, int n, int nbuck,
        int* __restrict__ row_ptr, float* __restrict__ dinv, float* __restrict__ xs,
        int* __restrict__ csr) {
    __shared__ int cnt[256], lcur[256];
    int b = blockIdx.x, t = threadIdx.x;
    cnt[t] = 0;
    __syncthreads();
    int lo = bucketBase[b];
    int hi = (b + 1 < nbuck) ? bucketBase[b + 1] : E;
    for (int e = lo + t; e < hi; e += 256)
        atomicAdd(&cnt[binned[e] >> 24], 1);
    __syncthreads();
    int c = cnt[t];
    lcur[t] = c;
    __syncthreads();
    for (int off = 1; off < 256; off <<= 1) {
        int u = (t >= off) ? lcur[t - off] : 0;
        __syncthreads();
        lcur[t] += u;
        __syncthreads();
    }
    int node0 = b << shift;
    int nodeEnd = min(n, (b + 1) << shift);
    int cntNodes = nodeEnd - node0;
    int myBase = lo + lcur[t] - c;  // exclusive prefix within bucket
    if (t < cntNodes) {
        row_ptr[node0 + t] = myBase;
        dinv[node0 + t] = rsqrtf((float)(c + 1));  // +1 self-loop
    }
    if (b == nbuck - 1 && t == 0) row_ptr[n] = E;
    for (int j = t; j < cntNodes * 9; j += 256) {
        int nl = j / 9, f = j - nl * 9;
        float dnl = rsqrtf((float)(cnt[nl] + 1));
        xs[(size_t)(node0 + nl) * 9 + f] = dnl * x[(size_t)(node0 + nl) * 9 + f];
    }
    __syncthreads();
    lcur[t] = myBase;  // running cursors
    __syncthreads();
    for (int e = lo + t; e < hi; e += 256) {
        uint p = binned[e];
        int pos = atomicAdd(&lcur[p >> 24], 1);
        csr[pos] = (int)(p & 0xFFFFFF);
    }
}

// ---------------- Layer 1 aggregate: aggx_bf = bf16(dinv .* (sum xs)) [node][32] ----------------
// Output padded to K=32 (cols 9..31 zero) in bf16: directly MFMA-A-consumable.

__global__ __launch_bounds__(256) void k_agg1(const float* __restrict__ xs,
                       const float* __restrict__ dinv,
                       const int* __restrict__ row_ptr, const int* __restrict__ csr,
                       __hip_bfloat16* __restrict__ aggx_bf, int n) {
    int node = blockIdx.x * 16 + (threadIdx.x >> 4);
    if (node >= n) return;
    int f = threadIdx.x & 15;
    bool act = f < 9;
    float acc = act ? xs[node * 9 + f] : 0.f;  // self-loop (xs = dinv*x)
    int e0 = row_ptr[node], e1 = row_ptr[node + 1];
    int e = e0;
    for (; e + 4 <= e1; e += 4) {
        int s0 = csr[e], s1 = csr[e + 1], s2 = csr[e + 2], s3 = csr[e + 3];
        float x0 = act ? xs[s0 * 9 + f] : 0.f;
        float x1 = act ? xs[s1 * 9 + f] : 0.f;
        float x2 = act ? xs[s2 * 9 + f] : 0.f;
        float x3 = act ? xs[s3 * 9 + f] : 0.f;
        acc += (x0 + x1) + (x2 + x3);
    }
    for (; e < e1; ++e) {
        int sA = csr[e];
        acc += act ? xs[sA * 9 + f] : 0.f;
    }
    float v = act ? dinv[node] * acc : 0.f;
    __hip_bfloat16* op = aggx_bf + (size_t)node * 32;
    union { __hip_bfloat16 h; short s; } u;
    u.h = __float2bfloat16(v);
    reinterpret_cast<short*>(op)[f] = u.s;
    reinterpret_cast<short*>(op)[16 + f] = 0;
}

// ---------------- W1 B-fragment prebuild: W1frag[ctile][lane][8] bf16 ----------------
// B-frag (16x16x32): lane holds B[k=quad*8+j][col=ctile*16+(lane&15)], k>=9 -> 0.

__global__ __launch_bounds__(256) void k_w1frag(const float* __restrict__ W1,
                                                __hip_bfloat16* __restrict__ W1frag) {
    int t = blockIdx.x * 256 + threadIdx.x;  // 2048 total
    if (t >= 32 * 64) return;
    int ctile = t >> 6, lane = t & 63;
    int col = ctile * 16 + (lane & 15);
    int k0 = (lane >> 4) * 8;
    short8 o;
#pragma unroll
    for (int j = 0; j < 8; ++j) {
        int k = k0 + j;
        o[j] = f2bf_bits(k < 9 ? W1[k * 512 + col] : 0.f);
    }
    *reinterpret_cast<short8*>(W1frag + (size_t)t * 8) = o;
}

// ---------------- Fused layer1-MFMA + layer2 GEMM ----------------
// BEST CONFIG (r18, 195.1us): h1 16-col tile = one verified 16x16x32 bf16 MFMA
// (K padded to 32); C-layout -> A-layout via same-wave private LDS round-trip
// (no barrier); W1 B-frags pre-built lane-contiguous; 196 blocks = one round,
// 2 tiles/wave. r19's tweaks (btot fold, 256-block spread) regressed -- keep this.
__global__ __launch_bounds__(512, 2) void k_l12(const __hip_bfloat16* __restrict__ aggx_bf,
                       const __hip_bfloat16* __restrict__ W1frag, const float* __restrict__ b1,
                       const float* __restrict__ W2, const float* __restrict__ dinv,
                       __hip_bfloat16* __restrict__ t2, int n, int npair) {
    __shared__ short bsh[64 * 128 * 8];  // 128 KB: [kb 0..63][c 0..127][j 0..7]
    __shared__ short h1s[8][16][40];     // 10 KB: per-wave 16 rows x 32 cols, stride 40
    int t = threadIdx.x;

    // Stage all 128 cols of W2 (fp32 -> bf16) into LDS.
    for (int idx = t; idx < 64 * 128; idx += 512) {
        int kb = idx >> 7, c = idx & 127;
        const float* wp = W2 + (size_t)(kb * 8) * 128 + c;
        short8 o;
#pragma unroll
        for (int j = 0; j < 8; ++j) o[j] = f2bf_bits(wp[j * 128]);
        *reinterpret_cast<short8*>(bsh + (size_t)idx * 8) = o;
    }
    __syncthreads();

    int wid = t >> 6, lane = t & 63;
    int pair = blockIdx.x * 8 + wid;
    if (pair >= npair) return;
    int r = lane & 15, quad = lane >> 4;
    short (*hs)[40] = h1s[wid];

#pragma unroll
    for (int half = 0; half < 2; ++half) {
        int m0 = (pair << 5) + half * 16;
        // A-frag for h1-GEMM: aggx_bf[m0+r][quad*8+j] (padded rows OOB-safe)
        short8 aagg = *reinterpret_cast<const short8*>(
            aggx_bf + (size_t)(m0 + r) * 32 + quad * 8);

        float4v acc[8];
#pragma unroll
        for (int cg = 0; cg < 8; ++cg) acc[cg] = (float4v){0, 0, 0, 0};

        for (int kt = 0; kt < 16; ++kt) {
            // h1 cols [kt*32, kt*32+32): two 16-col MFMAs
            short8 bf0 = *reinterpret_cast<const short8*>(
                W1frag + ((size_t)(2 * kt) * 64 + lane) * 8);
            short8 bf1 = *reinterpret_cast<const short8*>(
                W1frag + ((size_t)(2 * kt + 1) * 64 + lane) * 8);
            float4v c0 = __builtin_amdgcn_mfma_f32_16x16x32_bf16(
                aagg, bf0, (float4v){0, 0, 0, 0}, 0, 0, 0);
            float4v c1 = __builtin_amdgcn_mfma_f32_16x16x32_bf16(
                aagg, bf1, (float4v){0, 0, 0, 0}, 0, 0, 0);
            float bb0 = b1[kt * 32 + r];
            float bb1 = b1[kt * 32 + 16 + r];
            // C-layout (col=lane&15, row=quad*4+i) -> LDS [row][col]
#pragma unroll
            for (int i = 0; i < 4; ++i) {
                int row = quad * 4 + i;
                hs[row][r]      = f2bf_bits(fmaxf(c0[i] + bb0, 0.f));
                hs[row][16 + r] = f2bf_bits(fmaxf(c1[i] + bb1, 0.f));
            }
            // same-wave read back in A-layout: A[m=r][k=quad*8+j]
            short8 am = *reinterpret_cast<const short8*>(&hs[r][quad * 8]);
#pragma unroll
            for (int cg = 0; cg < 8; ++cg) {
                short8 b = *reinterpret_cast<const short8*>(
                    bsh + (size_t)(((kt * 4 + quad) * 128) + cg * 16 + r) * 8);
                acc[cg] = __builtin_amdgcn_mfma_f32_16x16x32_bf16(am, b, acc[cg], 0, 0, 0);
            }
        }

        // Epilogue: C/D col = lane&15, row = quad*4 + reg; scale row by dinv[node]
#pragma unroll
        for (int i = 0; i < 4; ++i) {
            int node = m0 + quad * 4 + i;
            if (node < n) {
                float di = dinv[node];
                __hip_bfloat16* op = t2 + (size_t)node * 128 + r;
#pragma unroll
                for (int cg = 0; cg < 8; ++cg)
                    op[cg * 16] = __float2bfloat16(di * acc[cg][i]);
            }
        }
    }
}

// ---------------- Layer 2 aggregate + fused layer-3 matmul ----------------

__global__ __launch_bounds__(256) void k_agg2(const uint* __restrict__ t2u,
                       const float* __restrict__ dinv,
                       const int* __restrict__ row_ptr, const int* __restrict__ csr,
                       const float* __restrict__ b2, const float* __restrict__ W3,
                       float2* __restrict__ t3, int n) {
    int node = blockIdx.x * 4 + (threadIdx.x >> 6);
    if (node >= n) return;
    int lane = threadIdx.x & 63;
    float2 p = up_bf2(t2u[(size_t)node * 64 + lane]);  // self (t2' = dinv*t2)
    float a0 = p.x, a1 = p.y;
    int e0 = row_ptr[node], e1 = row_ptr[node + 1];
    int e = e0;
    for (; e + 8 <= e1; e += 8) {
        int si[8];
        uint ri[8];
#pragma unroll
        for (int j = 0; j < 8; ++j) si[j] = csr[e + j];
#pragma unroll
        for (int j = 0; j < 8; ++j) ri[j] = t2u[(size_t)si[j] * 64 + lane];
#pragma unroll
        for (int j = 0; j < 8; ++j) {
            float2 q = up_bf2(ri[j]);
            a0 += q.x;
            a1 += q.y;
        }
    }
    for (; e + 2 <= e1; e += 2) {
        int s0 = csr[e], s1 = csr[e + 1];
        uint r0 = t2u[(size_t)s0 * 64 + lane];
        uint r1 = t2u[(size_t)s1 * 64 + lane];
        float2 q0 = up_bf2(r0), q1 = up_bf2(r1);
        a0 += q0.x + q1.x;
        a1 += q0.y + q1.y;
    }
    if (e < e1) {
        float2 q0 = up_bf2(t2u[(size_t)csr[e] * 64 + lane]);
        a0 += q0.x;
        a1 += q0.y;
    }
    float di = dinv[node];
    float2 bb = *reinterpret_cast<const float2*>(b2 + 2 * lane);
    float h0 = fmaxf(di * a0 + bb.x, 0.f);
    float h1v = fmaxf(di * a1 + bb.y, 0.f);
    float4 wv = *reinterpret_cast<const float4*>(W3 + 4 * lane);
    float c0 = h0 * wv.x + h1v * wv.z;
    float c1 = h0 * wv.y + h1v * wv.w;
#pragma unroll
    for (int off = 32; off; off >>= 1) {
        c0 += __shfl_xor(c0, off);
        c1 += __shfl_xor(c1, off);
    }
    if (lane == 0) t3[node] = make_float2(di * c0, di * c1);  // prescaled
}

// ---------------- Layer 3 aggregate + log_softmax ----------------

__global__ void k_agg3(const float2* __restrict__ t3, const float* __restrict__ dinv,
                       const int* __restrict__ row_ptr, const int* __restrict__ csr,
                       const float* __restrict__ b3, float2* __restrict__ outv, int n) {
    int node = blockIdx.x * blockDim.x + threadIdx.x;
    if (node >= n) return;
    float2 s = t3[node];  // self (t3' = dinv*t3)
    float a0 = s.x, a1 = s.y;
    int e0 = row_ptr[node], e1 = row_ptr[node + 1];
    int e = e0;
    for (; e + 4 <= e1; e += 4) {
        int s0 = csr[e], s1 = csr[e + 1], s2 = csr[e + 2], s3 = csr[e + 3];
        float2 q0 = t3[s0], q1 = t3[s1], q2 = t3[s2], q3 = t3[s3];
        a0 += q0.x + q1.x + q2.x + q3.x;
        a1 += q0.y + q1.y + q2.y + q3.y;
    }
    for (; e < e1; ++e) {
        float2 q0 = t3[csr[e]];
        a0 += q0.x;
        a1 += q0.y;
    }
    float di = dinv[node];
    float z0 = di * a0 + b3[0];
    float z1 = di * a1 + b3[1];
    float m = fmaxf(z0, z1);
    float lse = m + logf(expf(z0 - m) + expf(z1 - m));
    outv[node] = make_float2(z0 - lse, z1 - lse);
}

// ---------------- launch ----------------

extern "C" void kernel_launch(void* const* d_in, const int* in_sizes, int n_in,
                              void* d_out, int out_size, void* d_ws, size_t ws_size,
                              hipStream_t stream) {
    const float* x  = (const float*)d_in[0];
    const float* W1 = (const float*)d_in[1];
    const float* b1 = (const float*)d_in[2];
    const float* W2 = (const float*)d_in[3];
    const float* b2 = (const float*)d_in[4];
    const float* W3 = (const float*)d_in[5];
    const float* b3 = (const float*)d_in[6];
    const int* edges = (const int*)d_in[7];

    int n = in_sizes[0] / 9;
    int E = in_sizes[7] / 2;
    const int* src = edges;
    const int* dst = edges + E;

    char* p = (char*)d_ws;
    auto alloc = [&](size_t bytes) {
        char* q = p;
        p += (bytes + 511) & ~(size_t)511;
        return q;
    };
    float* dinv       = (float*)alloc((size_t)n * 4);
    int*   row_ptr    = (int*)alloc((size_t)(n + 1) * 4);
    int*   csr        = (int*)alloc((size_t)E * 4);
    int*   histBlk    = (int*)alloc((size_t)256 * NBLK * 4);
    int*   baseBlk    = (int*)alloc((size_t)256 * NBLK * 4);
    int*   btot       = (int*)alloc(256 * 4);
    int*   bucketBase = (int*)alloc(256 * 4);
    uint*  binned     = (uint*)alloc((size_t)E * 4);
    float* xs         = (float*)alloc((size_t)n * 9 * 4);
    __hip_bfloat16* aggx_bf = (__hip_bfloat16*)alloc((size_t)(n + 64) * 32 * 2);
    __hip_bfloat16* W1frag  = (__hip_bfloat16*)alloc((size_t)32 * 64 * 8 * 2);
    __hip_bfloat16* t2 = (__hip_bfloat16*)alloc((size_t)n * 128 * 2);
    float2* t3 = (float2*)alloc((size_t)n * 8);

    const int B = 256;
    int shift = 8;  // packed binned requires shift==8 (dst_local 8b) and n < 2^24
    int nbuck = ((n - 1) >> shift) + 1;
    int chunk = (E + NBLK - 1) / NBLK;

    k_hist<<<NBLK, B, 0, stream>>>(dst, E, chunk, shift, nbuck, histBlk);
    k_btot<<<nbuck, B, 0, stream>>>(histBlk, btot);
    k_bscan<<<nbuck, B, 0, stream>>>(histBlk, btot, nbuck, baseBlk, bucketBase);
    k_scatterbin<<<NBLK, B, 0, stream>>>(src, dst, E, chunk, shift, nbuck, baseBlk, binned);
    k_csrbuild<<<nbuck, B, 0, stream>>>(binned, bucketBase, x, E, shift, n, nbuck,
                                        row_ptr, dinv, xs, csr);

    k_w1frag<<<8, B, 0, stream>>>(W1, W1frag);
    k_agg1<<<(n + 15) / 16, B, 0, stream>>>(xs, dinv, row_ptr, csr, aggx_bf, n);

    int ntile = (n + 15) / 16;            // 3125
    int npair = (ntile + 1) / 2;          // 1563 wave-tasks (last pair half-guarded)
    k_l12<<<(npair + 7) / 8, 512, 0, stream>>>(aggx_bf, W1frag, b1, W2, dinv, t2, n, npair);
    k_agg2<<<(n + 3) / 4, 256, 0, stream>>>((const uint*)t2, dinv, row_ptr, csr, b2, W3, t3, n);

    k_agg3<<<(n + B - 1) / B, B, 0, stream>>>(t3, dinv, row_ptr, csr, b3, (float2*)d_out, n);
}